// Round 4
// baseline (1226.243 us; speedup 1.0000x reference)
//
#include <hip/hip_runtime.h>
#include <hip/hip_bf16.h>
#include <stdint.h>

typedef __attribute__((ext_vector_type(8))) short short8;
typedef __attribute__((ext_vector_type(4))) float floatx4;

typedef __attribute__((address_space(3))) char lds_char;
typedef __attribute__((address_space(3))) const short8 lds_cshort8;

namespace {

constexpr int  BB  = 16;    // batch
constexpr int  E_  = 8;     // experts
constexpr int  CAP = 1024;  // capacity per expert (EC/E)
constexpr int  D_  = 512;   // d_model
constexpr int  F_  = 2048;  // d_ff
constexpr long EC_ = (long)E_ * CAP;   // 8192
constexpr long M_  = (long)BB * CAP;   // 16384 rows per expert

constexpr int BM = 128, BN = 256, BK = 32;
constexpr int NT = 256;                // 4 waves: 2 (M) x 2 (N)

static_assert(M_ % BM == 0 && D_ % BN == 0, "tile divisibility");

__device__ __forceinline__ float gelu_tanh(float x) {
    const float k0 = 0.7978845608028654f;  // sqrt(2/pi)
    const float k1 = 0.044715f;
    float u = k0 * x * (1.0f + k1 * x * x);
    float t = 1.0f - 2.0f / (__expf(2.0f * u) + 1.0f);
    return 0.5f * x * (1.0f + t);
}

// T3-minimum 2-phase GEMM, B^T input. 128x256x32 tile, 4 waves, dbuf LDS 48KiB
// -> 2 workgroups/CU (the cross-WG overlap is the point: barriers/prologue/
// epilogue of one WG hide under the other's compute).
//   A rows:  addr = e*sAe + b*sAb + c*K       (m = b*CAP + c, row length == K)
//   B rows:  addr = e*sBe + n*ldb + k         (N x K, k-contiguous)
//   Out:     addr = e*sOe + b*sOb + c*ldo + n
// EPI: 0 = +bias, gelu, bf16 store   1 = +bias, f32 store   2 = f32 accumulate
template <int EPI>
__global__ __launch_bounds__(NT, 2) void gemm2p(
    const __hip_bfloat16* __restrict__ A,
    const __hip_bfloat16* __restrict__ Bt,
    const float* __restrict__ bias, void* __restrict__ Out,
    const int K, const int ldb, const int ldo,
    const long sAb, const long sAe,
    const long sBe, const int biasE,
    const long sOb, const long sOe)
{
    // A: [2][128][32] bf16 = 2*8KiB, B: [2][256][32] bf16 = 2*16KiB. 48 KiB.
    __shared__ __align__(16) __hip_bfloat16 smem[24576];
    lds_char* const LA = (lds_char*)smem;          // A bufs: +c*8192
    lds_char* const LBp = (lds_char*)smem + 16384; // B bufs: +c*16384

    // bijective XCD swizzle on the flattened grid (nwg % 8 == 0 by construction)
    const int gx = (int)gridDim.x, gy = (int)gridDim.y;
    const int nwg = gx * gy * (int)gridDim.z;
    int id = (int)blockIdx.x + gx * ((int)blockIdx.y + gy * (int)blockIdx.z);
    id = (id & 7) * (nwg >> 3) + (id >> 3);
    const int nt = id % gx;
    const int mt = (id / gx) % gy;
    const int e  = id / (gx * gy);
    const int m0 = mt * BM;
    const int n0 = nt * BN;

    const int tid  = (int)threadIdx.x;
    const int lane = tid & 63;
    const int w    = tid >> 6;        // 0..3
    const int wm   = (w >> 1) * 64;   // wave's m offset in tile
    const int wn   = (w & 1) * 128;   // wave's n offset in tile
    const int fr   = lane & 15;
    const int fq   = lane >> 4;

    const int nK = K >> 5;            // K-tiles of 32

    const __hip_bfloat16* const Ae = A  + (long)e * sAe;
    const __hip_bfloat16* const Be = Bt + (long)e * sBe + (long)n0 * ldb;

    // Staging: each 1024B wave-instr = 16 rows x 64B, linear LDS dest
    // (base + lane*16). Source column pre-swizzled so the XOR'd read is correct:
    // physical col16 p of row r holds logical col p ^ ((r>>1)&3).
    const int skB_ = ((lane & 3) ^ ((lane >> 3) & 3)) * 16;   // bytes in 64B row
    const char* aP[2];
    const char* bP[4];
#pragma unroll
    for (int t = 0; t < 2; ++t) {
        const int ra = w * 32 + t * 16 + (lane >> 2);
        const int mg = m0 + ra;
        const int b  = mg >> 10;             // CAP = 1024
        const int c  = mg & (CAP - 1);
        aP[t] = (const char*)Ae + ((long)b * sAb + (long)c * K) * 2 + skB_;
    }
#pragma unroll
    for (int t = 0; t < 4; ++t) {
        const int nr = w * 64 + t * 16 + (lane >> 2);
        bP[t] = (const char*)Be + (long)nr * ldb * 2 + skB_;
    }

    // ds_read side: logical col16 = fq  ->  physical (fq ^ ((fr>>1)&3)) * 16
    const int cbr = (fq ^ ((fr >> 1) & 3)) << 4;

#define STAGE(CB, KT)                                                              \
    do {                                                                           \
        if ((KT) < nK) {                                                           \
            const long kb_ = (long)(KT) * 64;  /* 32 bf16 = 64B along K */         \
            _Pragma("unroll")                                                      \
            for (int t = 0; t < 2; ++t)                                            \
                __builtin_amdgcn_global_load_lds(                                  \
                    (const __attribute__((address_space(1))) void*)(aP[t] + kb_),  \
                    (__attribute__((address_space(3))) void*)(LA + (CB) * 8192 +   \
                        w * 2048 + t * 1024), 16, 0, 0);                           \
            _Pragma("unroll")                                                      \
            for (int t = 0; t < 4; ++t)                                            \
                __builtin_amdgcn_global_load_lds(                                  \
                    (const __attribute__((address_space(1))) void*)(bP[t] + kb_),  \
                    (__attribute__((address_space(3))) void*)(LBp + (CB) * 16384 + \
                        w * 4096 + t * 1024), 16, 0, 0);                           \
        }                                                                          \
    } while (0)

    floatx4 acc[4][8] = {};

    STAGE(0, 0);
    __syncthreads();

    int c = 0;
    for (int kt = 0; kt < nK; ++kt) {
        STAGE(c ^ 1, kt + 1);   // issue next tile first: latency hides under compute

        short8 af[4], bf[8];
#pragma unroll
        for (int i = 0; i < 4; ++i)
            af[i] = *(lds_cshort8*)(LA + c * 8192 + (wm + i * 16 + fr) * 64 + cbr);
#pragma unroll
        for (int j = 0; j < 8; ++j)
            bf[j] = *(lds_cshort8*)(LBp + c * 16384 + (wn + j * 16 + fr) * 64 + cbr);

#pragma unroll
        for (int i = 0; i < 4; ++i)
#pragma unroll
            for (int j = 0; j < 8; ++j)
                acc[i][j] = __builtin_amdgcn_mfma_f32_16x16x32_bf16(
                    af[i], bf[j], acc[i][j], 0, 0, 0);

        __syncthreads();        // drains lgkm (reads already consumed) + vm (next tile)
        c ^= 1;
    }

    // epilogue: C/D layout col = lane&15, row = (lane>>4)*4 + r
    float bv[8];
#pragma unroll
    for (int j = 0; j < 8; ++j) {
        if constexpr (EPI != 2)
            bv[j] = bias[(long)e * biasE + n0 + wn + j * 16 + fr];
        else
            bv[j] = 0.0f;
    }
#pragma unroll
    for (int i = 0; i < 4; ++i) {
#pragma unroll
        for (int r = 0; r < 4; ++r) {
            const int mg = m0 + wm + i * 16 + fq * 4 + r;
            const int b  = mg >> 10;
            const int cc = mg & (CAP - 1);
            const long ro = (long)b * sOb + (long)e * sOe + (long)cc * ldo;
#pragma unroll
            for (int j = 0; j < 8; ++j) {
                const int ng = n0 + wn + j * 16 + fr;
                if constexpr (EPI == 0) {
                    ((__hip_bfloat16*)Out)[ro + ng] =
                        __float2bfloat16(gelu_tanh(acc[i][j][r] + bv[j]));
                } else if constexpr (EPI == 1) {
                    ((float*)Out)[ro + ng] = acc[i][j][r] + bv[j];
                } else {
                    ((float*)Out)[ro + ng] += acc[i][j][r];
                }
            }
        }
    }
#undef STAGE
}

__global__ __launch_bounds__(256) void cvt_f32_bf16(
    const float* __restrict__ in, __hip_bfloat16* __restrict__ out, const long n)
{
    long i = ((long)blockIdx.x * blockDim.x + threadIdx.x) * 4;
    const long stride = (long)gridDim.x * blockDim.x * 4;
    for (; i < n; i += stride) {
        const float4 v = *(const float4*)(in + i);
        __hip_bfloat16 t0 = __float2bfloat16(v.x);
        __hip_bfloat16 t1 = __float2bfloat16(v.y);
        __hip_bfloat16 t2 = __float2bfloat16(v.z);
        __hip_bfloat16 t3 = __float2bfloat16(v.w);
        ushort4 o;
        o.x = *(unsigned short*)&t0;
        o.y = *(unsigned short*)&t1;
        o.z = *(unsigned short*)&t2;
        o.w = *(unsigned short*)&t3;
        *(ushort4*)(out + i) = o;
    }
}

// per-expert transpose (R x Cc) fp32 -> (Cc x R) bf16
__global__ __launch_bounds__(256) void transpose_cvt(
    const float* __restrict__ in, __hip_bfloat16* __restrict__ out,
    const int R, const int Cc)
{
    __shared__ float tile[32][33];
    const int e = blockIdx.z;
    const float* pin = in + (long)e * R * Cc;
    __hip_bfloat16* pout = out + (long)e * R * Cc;
    const int c0 = blockIdx.x * 32;
    const int r0 = blockIdx.y * 32;
    const int tx = threadIdx.x & 31;
    const int ty = threadIdx.x >> 5;  // 0..7
#pragma unroll
    for (int rr = ty; rr < 32; rr += 8)
        tile[rr][tx] = pin[(long)(r0 + rr) * Cc + c0 + tx];
    __syncthreads();
#pragma unroll
    for (int rr = ty; rr < 32; rr += 8)
        pout[(long)(c0 + rr) * R + r0 + tx] = __float2bfloat16(tile[tx][rr]);
}

}  // namespace

extern "C" void kernel_launch(void* const* d_in, const int* in_sizes, int n_in,
                              void* d_out, int out_size, void* d_ws, size_t ws_size,
                              hipStream_t stream) {
    const float* x  = (const float*)d_in[0];
    const float* w1 = (const float*)d_in[1];
    const float* b1 = (const float*)d_in[2];
    const float* w2 = (const float*)d_in[3];
    const float* b2 = (const float*)d_in[4];
    float* out = (float*)d_out;

    const long nX  = (long)BB * EC_ * D_;  // 67,108,864
    const long nW1 = (long)E_ * D_ * F_;   //  8,388,608
    const long nW2 = nW1;

    __hip_bfloat16* xb  = (__hip_bfloat16*)d_ws;
    __hip_bfloat16* w1t = xb + nX;
    __hip_bfloat16* w2t = w1t + nW1;
    __hip_bfloat16* h   = w2t + nW2;

    const size_t fixed = (size_t)(nX + nW1 + nW2) * 2;  // 160 MiB

    // largest F-chunk whose h-buffer fits the workspace (must be % BN == 0)
    int Fc = 0;
    for (int cand : {2048, 1024, 512, 256}) {
        size_t need = fixed + (size_t)BB * EC_ * cand * 2;
        if (need <= ws_size) { Fc = cand; break; }
    }
    if (Fc == 0) return;  // workspace too small — fail visibly

    // 1) x -> bf16
    cvt_f32_bf16<<<dim3(32768), dim3(256), 0, stream>>>(x, xb, nX);
    // 2) w1 (E,D,F) -> w1t (E,F,D) bf16
    transpose_cvt<<<dim3(F_ / 32, D_ / 32, E_), dim3(256), 0, stream>>>(w1, w1t, D_, F_);
    // 3) w2 (E,F,D) -> w2t (E,D,F) bf16
    transpose_cvt<<<dim3(D_ / 32, F_ / 32, E_), dim3(256), 0, stream>>>(w2, w2t, F_, D_);

    for (int f0 = 0; f0 < F_; f0 += Fc) {
        // GEMM1 chunk: h(b,e,c, 0..Fc) = gelu(x @ w1[:, f0:f0+Fc] + b1[f0:...])
        gemm2p<0><<<dim3(Fc / BN, (int)(M_ / BM), E_), dim3(NT), 0, stream>>>(
            xb, w1t + (long)f0 * D_, b1 + f0, h,
            /*K=*/D_, /*ldb=*/D_, /*ldo=*/Fc,
            /*sAb=*/EC_ * D_, /*sAe=*/(long)CAP * D_,
            /*sBe=*/(long)F_ * D_, /*biasE=*/F_,
            /*sOb=*/(long)E_ * CAP * Fc, /*sOe=*/(long)CAP * Fc);

        // GEMM2 chunk: y (+)= h_chunk @ w2[f0:f0+Fc, :]  (+ b2 on first chunk)
        if (f0 == 0) {
            gemm2p<1><<<dim3(D_ / BN, (int)(M_ / BM), E_), dim3(NT), 0, stream>>>(
                h, w2t + f0, b2, out,
                /*K=*/Fc, /*ldb=*/F_, /*ldo=*/D_,
                /*sAb=*/(long)E_ * CAP * Fc, /*sAe=*/(long)CAP * Fc,
                /*sBe=*/(long)D_ * F_, /*biasE=*/D_,
                /*sOb=*/EC_ * D_, /*sOe=*/(long)CAP * D_);
        } else {
            gemm2p<2><<<dim3(D_ / BN, (int)(M_ / BM), E_), dim3(NT), 0, stream>>>(
                h, w2t + f0, nullptr, out,
                /*K=*/Fc, /*ldb=*/F_, /*ldo=*/D_,
                /*sAb=*/(long)E_ * CAP * Fc, /*sAe=*/(long)CAP * Fc,
                /*sBe=*/(long)D_ * F_, /*biasE=*/D_,
                /*sOb=*/EC_ * D_, /*sOe=*/(long)CAP * D_);
        }
    }
}